// Round 11
// baseline (29550.104 us; speedup 1.0000x reference)
//
#include <hip/hip_runtime.h>
#include <stdint.h>

// MUCMA — round 11: round-8/10 block-pipelined 2-wave structure (1 barrier / 4
// symbols, lag algebra + wave B + gram7 unchanged) with wave A's complex math
// hand-encoded as VOP3P packed-f32 (v_pk_fma_f32 / v_pk_mul_f32 with
// op_sel / op_sel_hi / neg_hi). Each complex FMA = 2 instructions, broadcasts
// and re/im swaps are free via op_sel (round 9's v2f attempt failed because
// the compiler emitted movs instead). Corrections additionally split into two
// independent accumulator chains to halve dependency latency.
//
// Encodings (verified against round-8 scalar formulas):
//  corr:  v.lo += -hr*Sr + hi*Si ; v.hi += -hr*Si - hi*Sr       (2 pk_fma)
//  r:     a = OMB*v ; r = B*r ; r += {a.lo*z.lo, a.hi*z.lo} ; r += {a.hi*z.hi, -a.lo*z.hi}
//  q:     q = {r.lo*z.lo, r.hi*z.lo} ; q += {r.hi*z.hi, -r.lo*z.hi}
//  c':    c = {e2*v.lo, e2*v.hi} + {i2*q.lo, i2*q.hi}           (ei = {e2,i2})

typedef float v2f __attribute__((ext_vector_type(2)));
typedef float v4f __attribute__((ext_vector_type(4), aligned(8)));

constexpr int   NTAPS   = 19;
constexpr int   FRST    = 38;
constexpr float BETA_C  = 0.999f;
constexpr float OMB_C   = 0.001f;
constexpr float LR_C    = 0.0001220703125f;   // 2^-13
constexpr float R2_C    = 1.32f;
constexpr int   SPLIT_N = 24576;              // beta^(n+1) == 0 in f32 beyond; mult of 16

template <int CTRL>
__device__ __forceinline__ float dpp_add(float x) {
    return x + __int_as_float(__builtin_amdgcn_update_dpp(
        0, __float_as_int(x), CTRL, 0xF, 0xF, true));
}
template <int CTRL>
__device__ __forceinline__ float dpp_mov(float x) {
    return __int_as_float(__builtin_amdgcn_update_dpp(
        0, __float_as_int(x), CTRL, 0xF, 0xF, true));
}
__device__ __forceinline__ float rowred_bcast(float x) {
    x = dpp_add<0x121>(x);   // row_ror:1
    x = dpp_add<0x122>(x);   // row_ror:2
    x = dpp_add<0x124>(x);   // row_ror:4
    x = dpp_add<0x128>(x);   // row_ror:8
    return x;
}
__device__ __forceinline__ void plane32_swap(float& a, float& b) {
    asm("s_nop 1\n\t"
        "v_permlane32_swap_b32 %0, %1\n\t"
        "s_nop 1"
        : "+v"(a), "+v"(b));
}
__device__ __forceinline__ void plane32_swap2(float& a, float& b, float& c, float& d) {
    asm("s_nop 1\n\t"
        "v_permlane32_swap_b32 %0, %1\n\t"
        "v_permlane32_swap_b32 %2, %3\n\t"
        "s_nop 1"
        : "+v"(a), "+v"(b), "+v"(c), "+v"(d));
}
__device__ __forceinline__ void wg_barrier() {
    asm volatile("s_waitcnt lgkmcnt(0)\n\ts_barrier" ::: "memory");
}

// ---- VOP3P packed complex helpers ----
// acc += conj-free complex correction: acc.lo += -h.lo*S.lo + h.hi*S.hi
//                                      acc.hi += -h.lo*S.hi - h.hi*S.lo
__device__ __forceinline__ void cfma_pk(v2f& acc, v2f h, v2f S) {
    asm("v_pk_fma_f32 %0, %1, %2, %0 op_sel:[0,0,0] op_sel_hi:[0,1,1] neg_lo:[1,0,0] neg_hi:[1,0,0]\n\t"
        "v_pk_fma_f32 %0, %1, %2, %0 op_sel:[1,1,0] op_sel_hi:[1,0,1] neg_lo:[0,0,0] neg_hi:[1,0,0]"
        : "+v"(acc) : "v"(h), "v"(S));
}
// r = bc.lo*r + (bc.hi*v)*conj-mult with z ;  bc = {BETA, OMB}
__device__ __forceinline__ void rupd_pk(v2f& r, v2f bc, v2f v, v2f z) {
    v2f a;
    asm("v_pk_mul_f32 %0, %1, %2 op_sel:[1,0] op_sel_hi:[1,1]"                // a = OMB*v
        : "=v"(a) : "v"(bc), "v"(v));
    asm("v_pk_mul_f32 %0, %1, %0 op_sel:[0,0] op_sel_hi:[0,1]"                // r *= BETA
        : "+v"(r) : "v"(bc));
    asm("v_pk_fma_f32 %0, %1, %2, %0 op_sel:[0,0,0] op_sel_hi:[1,0,1]"        // += {ar*zre, ai*zre}
        : "+v"(r) : "v"(a), "v"(z));
    asm("v_pk_fma_f32 %0, %1, %2, %0 op_sel:[1,1,0] op_sel_hi:[0,1,1] neg_hi:[1,0,0]" // += {ai*zim, -ar*zim}
        : "+v"(r) : "v"(a), "v"(z));
}
// q = r (*) conj(z):  {r.lo*z.lo + r.hi*z.hi,  r.hi*z.lo - r.lo*z.hi}
__device__ __forceinline__ v2f qmul_pk(v2f r, v2f z) {
    v2f q;
    asm("v_pk_mul_f32 %0, %1, %2 op_sel:[0,0] op_sel_hi:[1,0]"
        : "=v"(q) : "v"(r), "v"(z));
    asm("v_pk_fma_f32 %0, %1, %2, %0 op_sel:[1,1,0] op_sel_hi:[0,1,1] neg_hi:[1,0,0]"
        : "+v"(q) : "v"(r), "v"(z));
    return q;
}
// c = ei.lo*v + ei.hi*q   (ei = {e2, i2})
__device__ __forceinline__ v2f cprime_pk(v2f ei, v2f v, v2f q) {
    v2f c;
    asm("v_pk_mul_f32 %0, %1, %2 op_sel:[0,0] op_sel_hi:[0,1]"
        : "=v"(c) : "v"(ei), "v"(v));
    asm("v_pk_fma_f32 %0, %1, %2, %0 op_sel:[1,0,0] op_sel_hi:[1,1,1]"
        : "+v"(c) : "v"(ei), "v"(q));
    return c;
}

// ---------- parallel precompute: SC[m][2(k-1)..] = S_k(m-k) = <conj u(m-k), u(m)> ----------
__global__ void __launch_bounds__(64)
gram7_kernel(const float* __restrict__ fr_re, const float* __restrict__ fr_im,
             float* __restrict__ sc, int nsym)
{
    __shared__ float lre[71 * FRST], lim[71 * FRST];
    const int lane = threadIdx.x;
    const int n0   = blockIdx.x * 64;
    const int base = (n0 - 7) * FRST;
    const long gmax = (long)nsym * FRST;
    for (int idx = lane; idx < 71 * FRST; idx += 64) {
        const long g = (long)base + idx;
        float a = 0.f, b = 0.f;
        if (g >= 0 && g < gmax) { a = fr_re[g]; b = fr_im[g]; }
        lre[idx] = a; lim[idx] = b;
    }
    __syncthreads();
    const int m = n0 + lane;
    if (m >= nsym) return;
    const float* br = lre + (lane + 7) * FRST;
    const float* bi = lim + (lane + 7) * FRST;
    float out[16];
#pragma unroll
    for (int k = 1; k <= 7; ++k) {
        const float* ar = br - k * FRST;
        const float* ai = bi - k * FRST;
        float sr = 0.f, si = 0.f;
#pragma unroll
        for (int e = 0; e < FRST; ++e) {
            sr = fmaf(ar[e], br[e], fmaf(ai[e], bi[e], sr));
            si = fmaf(-ai[e], br[e], fmaf(ar[e], bi[e], si));
        }
        const bool ok = (m >= k);
        out[2*(k-1)]   = ok ? sr : 0.f;
        out[2*(k-1)+1] = ok ? si : 0.f;
    }
    out[14] = 0.f; out[15] = 0.f;
    float* d = sc + (size_t)m * 16;
#pragma unroll
    for (int j = 0; j < 4; ++j)
        *(v4f*)(d + 4*j) = (v4f){out[4*j], out[4*j+1], out[4*j+2], out[4*j+3]};
}

// ---------- wave A ----------
struct A_St {
    v2f acor2[8];               // Acor ring
    v2f hist2[8];               // c' history ring (packed {cr,ci})
    v2f scr2[4][8];             // SC pairs: scr2[m&3][k-1] = {Sr,Si} of S_k
    v2f z2, r2, bc;             // z, r packed; bc = {BETA, OMB}
    float bp;
};
struct A_Ctx {
    const float* scp; float* outp;
    float (*aring)[2][32][2]; float (*cring)[2][32][2];
    int h, sl; bool d0f, csel; int last;
};

template <int S, bool EARLY, bool TAIL>
__device__ __forceinline__ void a_pos(A_St& st, const A_Ctx& c, int SB)
{
    constexpr int s8 = S & 7, s4 = S & 3, NC = 4 + (S & 3);
    const int m = SB + S;

    // ---- v(m) = Acor(m) - sum_{k=1..NC} c'(m-k)*S_k(m-k): two pk-fma chains ----
    v2f acc0 = st.acor2[s8];
    v2f acc1 = {0.f, 0.f};
#pragma unroll
    for (int k = 1; k <= NC; ++k) {
        if (k & 1) cfma_pk(acc0, st.hist2[(S - k) & 7], st.scr2[s4][k - 1]);
        else       cfma_pk(acc1, st.hist2[(S - k) & 7], st.scr2[s4][k - 1]);
    }
    const v2f v = acc0 + acc1;

    // emit v(m) (all 32 lanes of the half uniform -> same-addr store)
    *(v2f*)(c.outp + 4 * (size_t)m + 2 * c.h) = v;

    // cross-half v
    float Xr = v.x, Yr = v.x, Xi = v.y, Yi = v.y;
    plane32_swap2(Xr, Yr, Xi, Yi);
    const float vlr = c.csel ? Xr : Yr;
    const float vli = c.csel ? Xi : Yi;

    // z shift / insert
    const float zsr = dpp_mov<0x111>(st.z2.x);
    const float zsi = dpp_mov<0x111>(st.z2.y);
    st.z2.x = c.d0f ? vlr : zsr;
    st.z2.y = c.d0f ? vli : zsi;

    // r = beta*r + (1-beta)*v*conj(z)   (packed)
    rupd_pk(st.r2, st.bc, v, st.z2);

    // mu partials (packed) + row-broadcast sums
    const v2f q2 = qmul_pk(st.r2, st.z2);
    const float qr = rowred_bcast(q2.x);
    const float qi = rowred_bcast(q2.y);

    // c'(m)
    float i2;
    if (EARLY) {
        const float inv = __builtin_amdgcn_rcpf(1.0f - st.bp);
        st.bp *= BETA_C;
        i2 = (2.0f * LR_C) * inv;
    } else {
        i2 = 2.0f * LR_C;
    }
    const float tt = v.x * v.x + v.y * v.y;
    const float e2 = fmaf(2.0f * LR_C, tt, -(2.0f * LR_C) * R2_C);
    const v2f ei = {e2, i2};
    const v2f qv = {qr, qi};
    const v2f cp = cprime_pk(ei, v, qv);

    st.hist2[s8] = cp;
    *(v2f*)&c.cring[s8][c.h][c.sl][0] = cp;          // per-lane slots, conflict-free

    // SC prefetch for m+4 into the slot just consumed
    int mp = m + 4;
    if (TAIL) { if (mp > c.last) mp = c.last; }
    const float* p = c.scp + (size_t)mp * 16;
#pragma unroll
    for (int j = 0; j < 4; ++j) {
        const v4f sv = *(const v4f*)(p + 4 * j);
        st.scr2[s4][2*j]     = (v2f){sv.x, sv.y};
        st.scr2[s4][2*j + 1] = (v2f){sv.z, sv.w};
    }
}

template <int I, bool EARLY, bool TAIL>
__device__ __forceinline__ void a_sub(A_St& st, const A_Ctx& c, int SB)
{
#pragma unroll
    for (int t = 0; t < 4; ++t)
        st.acor2[(4*I + t) & 7] = *(const v2f*)&c.aring[(4*I + t) & 7][c.h][0][0];
    a_pos<4*I + 0, EARLY, TAIL>(st, c, SB);
    a_pos<4*I + 1, EARLY, TAIL>(st, c, SB);
    a_pos<4*I + 2, EARLY, TAIL>(st, c, SB);
    a_pos<4*I + 3, EARLY, TAIL>(st, c, SB);
    wg_barrier();
}
template <bool EARLY, bool TAIL>
__device__ __forceinline__ void a_super(A_St& st, const A_Ctx& c, int SB)
{
    a_sub<0, EARLY, TAIL>(st, c, SB);
    a_sub<1, EARLY, TAIL>(st, c, SB);
    a_sub<2, EARLY, TAIL>(st, c, SB);
    a_sub<3, EARLY, TAIL>(st, c, SB);
}

// ---------- wave B (identical to round 8/10) ----------
struct B_St {
    v2f wA_r, wA_i, wB_r, wB_i;
    v4f ur[16], ui[16];
    float mA, mB;
};
struct B_Ctx {
    const float* pre; const float* pim;
    float (*aring)[2][32][2]; float (*cring)[2][32][2];
    int h, sl; int last;
};

__device__ __forceinline__ v2f b_tree(const B_St& s, const v4f& uR, const v4f& uI) {
    const v2f uA_r = {uR.x,uR.y}, uB_r = {uR.z,uR.w};
    const v2f uA_i = {uI.x,uI.y}, uB_i = {uI.z,uI.w};
    v2f tr = s.wA_r*uA_r - s.wA_i*uA_i + s.wB_r*uB_r - s.wB_i*uB_i;
    v2f ti = s.wA_r*uA_i + s.wA_i*uA_r + s.wB_r*uB_i + s.wB_i*uB_r;
    return (v2f){ rowred_bcast(tr.x + tr.y), rowred_bcast(ti.x + ti.y) };
}

template <int I, bool TAIL>
__device__ __forceinline__ void b_sub(B_St& st, const B_Ctx& c, int SB)
{
    float ccr[4], cci[4];
#pragma unroll
    for (int t = 0; t < 4; ++t) {
        const v2f cc = *(const v2f*)&c.cring[(4*I + 4 + t) & 7][c.h][0][0];
        ccr[t] = cc.x; cci[t] = cc.y;
    }
#pragma unroll
    for (int t = 0; t < 4; ++t) {
        const float crA = ccr[t] * st.mA, ciA = cci[t] * st.mA;
        const float crB = ccr[t] * st.mB, ciB = cci[t] * st.mB;
        const v4f uR = st.ur[(4*I + 12 + t) & 15], uI = st.ui[(4*I + 12 + t) & 15];
        const v2f uA_r = {uR.x,uR.y}, uB_r = {uR.z,uR.w};
        const v2f uA_i = {uI.x,uI.y}, uB_i = {uI.z,uI.w};
        st.wA_r -= (v2f){crA,crA}*uA_r + (v2f){ciA,ciA}*uA_i;
        st.wA_i -= (v2f){ciA,ciA}*uA_r - (v2f){crA,crA}*uA_i;
        st.wB_r -= (v2f){crB,crB}*uB_r + (v2f){ciB,ciB}*uB_i;
        st.wB_i -= (v2f){ciB,ciB}*uB_r - (v2f){crB,crB}*uB_i;
    }
#pragma unroll
    for (int t = 0; t < 4; ++t) {
        const v2f T = b_tree(st, st.ur[(4*I + 4 + t) & 15], st.ui[(4*I + 4 + t) & 15]);
        *(v2f*)&c.aring[(4*I + 4 + t) & 7][c.h][c.sl][0] = T;
    }
#pragma unroll
    for (int t = 0; t < 4; ++t) {
        int f = SB + 4*I + 8 + t;
        if (TAIL) { if (f > c.last) f = c.last; }
        st.ur[(4*I + 8 + t) & 15] = *(const v4f*)(c.pre + (size_t)f * FRST);
        st.ui[(4*I + 8 + t) & 15] = *(const v4f*)(c.pim + (size_t)f * FRST);
    }
    wg_barrier();
}
template <bool TAIL>
__device__ __forceinline__ void b_super(B_St& st, const B_Ctx& c, int SB)
{
    b_sub<0, TAIL>(st, c, SB);
    b_sub<1, TAIL>(st, c, SB);
    b_sub<2, TAIL>(st, c, SB);
    b_sub<3, TAIL>(st, c, SB);
}

// ---------- 2-wave block-pipelined scan ----------
__global__ void __launch_bounds__(128, 1)
__attribute__((amdgpu_waves_per_eu(1, 1)))
mucma2d_kernel(const float* __restrict__ fr_re, const float* __restrict__ fr_im,
               const float* __restrict__ w0r_in, const float* __restrict__ w0i_in,
               const float* __restrict__ scp, float* __restrict__ outp, int nsym)
{
    __shared__ __align__(16) float cring[8][2][32][2];
    __shared__ __align__(16) float aring[8][2][32][2];

    const int  tid  = threadIdx.x;
    const int  wid  = tid >> 6;
    const int  lane = tid & 63;
    const int  sl   = lane & 31;
    const int  h    = lane >> 5;
    const int  loff = (4*sl < 34) ? 4*sl : 34;
    const int  last = nsym - 1;
    const int  SBend = nsym - 16;

    bool csel;
    { const float own = h ? 11.f : 7.f; float v = own, X = own;
      plane32_swap(X, v); csel = (X != own); }

    if (wid == 0) {
        // ================= wave A (chain) =================
        A_St st; A_Ctx c;
        c.scp = scp; c.outp = outp; c.aring = aring; c.cring = cring;
        c.h = h; c.sl = sl; c.d0f = ((sl & 15) == 10); c.csel = csel; c.last = last;
#pragma unroll
        for (int k = 0; k < 8; ++k) {
            st.hist2[k] = (v2f){0.f, 0.f};
            st.acor2[k] = (v2f){0.f, 0.f};
        }
        st.z2 = (v2f){0.f, 0.f}; st.r2 = (v2f){0.f, 0.f};
        st.bc = (v2f){BETA_C, OMB_C};
        st.bp = BETA_C;
#pragma unroll
        for (int s = 0; s < 4; ++s) {
            const float* p = scp + (size_t)s * 16;
#pragma unroll
            for (int j = 0; j < 4; ++j) {
                const v4f sv = *(const v4f*)(p + 4 * j);
                st.scr2[s][2*j]     = (v2f){sv.x, sv.y};
                st.scr2[s][2*j + 1] = (v2f){sv.z, sv.w};
            }
        }
        if (lane < 32) cring[lane >> 2][(lane >> 1) & 1][0][lane & 1] = 0.f;
        wg_barrier();

        int SB = 0;
        for (; SB < SPLIT_N; SB += 16) a_super<true , false>(st, c, SB);
        for (; SB < SBend;   SB += 16) a_super<false, false>(st, c, SB);
        a_super<false, true>(st, c, SB);
    } else {
        // ================= wave B (tree) =================
        B_St st; B_Ctx c;
        c.pre = fr_re + loff; c.pim = fr_im + loff;
        c.aring = aring; c.cring = cring; c.h = h; c.sl = sl; c.last = last;
        st.mA = (sl <= 8) ? 1.f : 0.f;
        st.mB = (sl <= 9) ? 1.f : 0.f;
        st.wA_r = (v2f){0.f,0.f}; st.wA_i = (v2f){0.f,0.f};
        st.wB_r = (v2f){0.f,0.f}; st.wB_i = (v2f){0.f,0.f};
        if (sl <= 8) {
            const int b = h*FRST + 2*sl;
            st.wA_r.x = w0r_in[b];       st.wA_r.y = w0r_in[b+NTAPS];
            st.wA_i.x = w0i_in[b];       st.wA_i.y = w0i_in[b+NTAPS];
            st.wB_r.x = w0r_in[b+1];     st.wB_r.y = w0r_in[b+NTAPS+1];
            st.wB_i.x = w0i_in[b+1];     st.wB_i.y = w0i_in[b+NTAPS+1];
        } else if (sl == 9) {
            st.wB_r.x = w0r_in[h*FRST+18];  st.wB_r.y = w0r_in[h*FRST+37];
            st.wB_i.x = w0i_in[h*FRST+18];  st.wB_i.y = w0i_in[h*FRST+37];
        }
#pragma unroll
        for (int k = 0; k < 12; ++k) {
            st.ur[k] = *(const v4f*)(c.pre + (size_t)k * FRST);
            st.ui[k] = *(const v4f*)(c.pim + (size_t)k * FRST);
        }
#pragma unroll
        for (int k = 12; k < 16; ++k) {
            st.ur[k] = (v4f){0.f,0.f,0.f,0.f};
            st.ui[k] = (v4f){0.f,0.f,0.f,0.f};
        }
#pragma unroll
        for (int t = 0; t < 4; ++t) {
            const v2f T = b_tree(st, st.ur[t], st.ui[t]);
            *(v2f*)&aring[t][h][sl][0] = T;
        }
        wg_barrier();

        int SB = 0;
        for (; SB < SBend; SB += 16) b_super<false>(st, c, SB);
        b_super<true>(st, c, SB);
    }
}

// ---------- fallback: round-4 single-wave kernel ----------
__global__ void __launch_bounds__(64, 1)
mucma_scan_fb(const float* __restrict__ fr_re, const float* __restrict__ fr_im,
              const float* __restrict__ w0r_in, const float* __restrict__ w0i_in,
              float* __restrict__ out, int nsym)
{
    const int  lane = threadIdx.x;
    const int  sl   = lane & 31;
    const int  h    = lane >> 5;
    const int  loff = (4 * sl < 34) ? 4 * sl : 34;
    const float mA  = (sl <= 8) ? 1.f : 0.f;
    const float mB  = (sl <= 9) ? 1.f : 0.f;
    const bool d0f  = (sl == 10);
    const bool stfl = (sl == 0);

    v2f wA_r = {0.f,0.f}, wA_i = {0.f,0.f}, wB_r = {0.f,0.f}, wB_i = {0.f,0.f};
    if (sl <= 8) {
        const int b = h * FRST + 2 * sl;
        wA_r.x = w0r_in[b];         wA_r.y = w0r_in[b + NTAPS];
        wA_i.x = w0i_in[b];         wA_i.y = w0i_in[b + NTAPS];
        wB_r.x = w0r_in[b + 1];     wB_r.y = w0r_in[b + NTAPS + 1];
        wB_i.x = w0i_in[b + 1];     wB_i.y = w0i_in[b + NTAPS + 1];
    } else if (sl == 9) {
        wB_r.x = w0r_in[h * FRST + 18];  wB_r.y = w0r_in[h * FRST + 37];
        wB_i.x = w0i_in[h * FRST + 18];  wB_i.y = w0i_in[h * FRST + 37];
    }
    float r_re = 0.f, r_im = 0.f, z_re = 0.f, z_im = 0.f;
    float bp = BETA_C;

    bool csel;
    {
        const float own = h ? 11.f : 7.f;
        float v = own, X = own;
        plane32_swap(X, v);
        csel = (X != own);
    }

    const float* pre = fr_re + loff;
    const float* pim = fr_im + loff;

    v4f rr[8], ri[8];
#pragma unroll
    for (int p = 0; p < 8; ++p) {
        const int idx = (p < nsym) ? p : (nsym - 1);
        rr[p] = *(const v4f*)(pre + (size_t)idx * FRST);
        ri[p] = *(const v4f*)(pim + (size_t)idx * FRST);
    }

    auto body = [&](int n, int p, int npf) {
        const v4f uR = rr[p], uI = ri[p];
        rr[p] = *(const v4f*)(pre + (size_t)npf * FRST);
        ri[p] = *(const v4f*)(pim + (size_t)npf * FRST);

        const v2f uA_r = {uR.x, uR.y}, uB_r = {uR.z, uR.w};
        const v2f uA_i = {uI.x, uI.y}, uB_i = {uI.z, uI.w};

        v2f tr = wA_r * uA_r - wA_i * uA_i + wB_r * uB_r - wB_i * uB_i;
        v2f ti = wA_r * uA_i + wA_i * uA_r + wB_r * uB_i + wB_i * uB_r;
        float xr = rowred_bcast(tr.x + tr.y);
        float xi = rowred_bcast(ti.x + ti.y);
        const float vkr = xr, vki = xi;

        float Xr = xr, Xi = xi;
        plane32_swap(Xr, xr);
        plane32_swap(Xi, xi);
        const float vlr = csel ? Xr : xr;
        const float vli = csel ? Xi : xi;

        const float zsr = dpp_mov<0x111>(z_re);
        const float zsi = dpp_mov<0x111>(z_im);
        z_re = d0f ? vlr : zsr;
        z_im = d0f ? vli : zsi;

        const float ar = OMB_C * vkr, ai = OMB_C * vki;
        r_re = BETA_C * r_re + (ar * z_re + ai * z_im);
        r_im = BETA_C * r_im + (ai * z_re - ar * z_im);

        float qr = r_re * z_re + r_im * z_im;
        float qi = r_im * z_re - r_re * z_im;
        qr = rowred_bcast(qr);
        qi = rowred_bcast(qi);

        const float inv = __builtin_amdgcn_rcpf(1.0f - bp);
        bp *= BETA_C;
        const float i2 = (2.0f * LR_C) * inv;
        const float ek = R2_C - (vkr * vkr + vki * vki);
        const float e2 = (-2.0f * LR_C) * ek;
        const float cr = e2 * vkr + i2 * qr;
        const float ci = e2 * vki + i2 * qi;

        const float crA = cr * mA, ciA = ci * mA;
        const float crB = cr * mB, ciB = ci * mB;
        wA_r -= (v2f){crA,crA} * uA_r + (v2f){ciA,ciA} * uA_i;
        wA_i -= (v2f){ciA,ciA} * uA_r - (v2f){crA,crA} * uA_i;
        wB_r -= (v2f){crB,crB} * uB_r + (v2f){ciB,ciB} * uB_i;
        wB_i -= (v2f){ciB,ciB} * uB_r - (v2f){crB,crB} * uB_i;

        if (stfl) {
            v2f o; o.x = vkr; o.y = vki;
            *(v2f*)(out + 4 * (size_t)n + 2 * h) = o;
        }
    };

    int NBmain = nsym / 8 - 1;
    if (NBmain < 0) NBmain = 0;
    for (int b = 0; b < NBmain; ++b) {
        const int nb = b * 8;
#pragma unroll
        for (int p = 0; p < 8; ++p) body(nb + p, p, nb + p + 8);
    }
    for (int nb = NBmain * 8; nb < nsym; nb += 8) {
#pragma unroll
        for (int p = 0; p < 8; ++p) {
            const int n = nb + p;
            if (n < nsym) {
                int npf = n + 8;
                if (npf > nsym - 1) npf = nsym - 1;
                body(n, p, npf);
            }
        }
    }
}

extern "C" void kernel_launch(void* const* d_in, const int* in_sizes, int n_in,
                              void* d_out, int out_size, void* d_ws, size_t ws_size,
                              hipStream_t stream)
{
    const float* fr_re = (const float*)d_in[0];
    const float* fr_im = (const float*)d_in[1];
    const float* w0r   = (const float*)d_in[2];
    const float* w0i   = (const float*)d_in[3];
    float* outp = (float*)d_out;
    const int nsym = in_sizes[0] / FRST;

    const bool use2 = (nsym % 16 == 0) && (nsym >= SPLIT_N + 16)
                   && (ws_size >= (size_t)nsym * 64);
    if (use2) {
        hipLaunchKernelGGL(gram7_kernel, dim3((nsym + 63) / 64), dim3(64), 0, stream,
                           fr_re, fr_im, (float*)d_ws, nsym);
        hipLaunchKernelGGL(mucma2d_kernel, dim3(1), dim3(128), 0, stream,
                           fr_re, fr_im, w0r, w0i, (const float*)d_ws, outp, nsym);
    } else {
        hipLaunchKernelGGL(mucma_scan_fb, dim3(1), dim3(64), 0, stream,
                           fr_re, fr_im, w0r, w0i, outp, nsym);
    }
}

// Round 12
// 28727.704 us; speedup vs baseline: 1.0286x; 1.0286x over previous
//
#include <hip/hip_runtime.h>
#include <stdint.h>

// MUCMA — round 12: round-8/10 two-wave block-pipelined structure (1 barrier /
// 4 symbols, lag algebra, wave B, gram7, rings verbatim) with wave A's chain
// restructured so the q-reduce tree runs IN PARALLEL with the permlane swap:
//  * d=0 of the r/z state split into uniform scalar recurrences
//      r0(m) = b*r0(m-1) + omb*v_k(m)*conj(v_l(m));  q0 = r0*conj(v_l)
//    -> vector z/r track only d=1..5; z shift+insert uses LAST step's v_l and
//       moves off-chain; the tree (r[d>=1]*conj(z)) starts right at v(m).
//  * ppre: k=2..NC correction terms for step m+1 pre-accumulated during step m;
//    on-chain correction is the single k=1 cfma.
// Chain/step: ~max(tree, swap+q0)+c' vs serial swap->z->r->q->tree->c' before.

typedef float v2f __attribute__((ext_vector_type(2)));
typedef float v4f __attribute__((ext_vector_type(4), aligned(8)));

constexpr int   NTAPS   = 19;
constexpr int   FRST    = 38;
constexpr float BETA_C  = 0.999f;
constexpr float OMB_C   = 0.001f;
constexpr float LR_C    = 0.0001220703125f;   // 2^-13
constexpr float R2_C    = 1.32f;
constexpr int   SPLIT_N = 24576;              // beta^(n+1) == 0 in f32 beyond; mult of 16

template <int CTRL>
__device__ __forceinline__ float dpp_add(float x) {
    return x + __int_as_float(__builtin_amdgcn_update_dpp(
        0, __float_as_int(x), CTRL, 0xF, 0xF, true));
}
template <int CTRL>
__device__ __forceinline__ float dpp_mov(float x) {
    return __int_as_float(__builtin_amdgcn_update_dpp(
        0, __float_as_int(x), CTRL, 0xF, 0xF, true));
}
__device__ __forceinline__ float rowred_bcast(float x) {
    x = dpp_add<0x121>(x);   // row_ror:1
    x = dpp_add<0x122>(x);   // row_ror:2
    x = dpp_add<0x124>(x);   // row_ror:4
    x = dpp_add<0x128>(x);   // row_ror:8
    return x;
}
__device__ __forceinline__ void plane32_swap(float& a, float& b) {
    asm("s_nop 1\n\t"
        "v_permlane32_swap_b32 %0, %1\n\t"
        "s_nop 1"
        : "+v"(a), "+v"(b));
}
__device__ __forceinline__ void plane32_swap2(float& a, float& b, float& c, float& d) {
    asm("s_nop 1\n\t"
        "v_permlane32_swap_b32 %0, %1\n\t"
        "v_permlane32_swap_b32 %2, %3\n\t"
        "s_nop 1"
        : "+v"(a), "+v"(b), "+v"(c), "+v"(d));
}
__device__ __forceinline__ void wg_barrier() {
    asm volatile("s_waitcnt lgkmcnt(0)\n\ts_barrier" ::: "memory");
}

// ---------- parallel precompute: SC[m][2(k-1)..] = S_k(m-k) = <conj u(m-k), u(m)> ----------
__global__ void __launch_bounds__(64)
gram7_kernel(const float* __restrict__ fr_re, const float* __restrict__ fr_im,
             float* __restrict__ sc, int nsym)
{
    __shared__ float lre[71 * FRST], lim[71 * FRST];
    const int lane = threadIdx.x;
    const int n0   = blockIdx.x * 64;
    const int base = (n0 - 7) * FRST;
    const long gmax = (long)nsym * FRST;
    for (int idx = lane; idx < 71 * FRST; idx += 64) {
        const long g = (long)base + idx;
        float a = 0.f, b = 0.f;
        if (g >= 0 && g < gmax) { a = fr_re[g]; b = fr_im[g]; }
        lre[idx] = a; lim[idx] = b;
    }
    __syncthreads();
    const int m = n0 + lane;
    if (m >= nsym) return;
    const float* br = lre + (lane + 7) * FRST;
    const float* bi = lim + (lane + 7) * FRST;
    float out[16];
#pragma unroll
    for (int k = 1; k <= 7; ++k) {
        const float* ar = br - k * FRST;
        const float* ai = bi - k * FRST;
        float sr = 0.f, si = 0.f;
#pragma unroll
        for (int e = 0; e < FRST; ++e) {
            sr = fmaf(ar[e], br[e], fmaf(ai[e], bi[e], sr));
            si = fmaf(-ai[e], br[e], fmaf(ar[e], bi[e], si));
        }
        const bool ok = (m >= k);
        out[2*(k-1)]   = ok ? sr : 0.f;
        out[2*(k-1)+1] = ok ? si : 0.f;
    }
    out[14] = 0.f; out[15] = 0.f;
    float* d = sc + (size_t)m * 16;
#pragma unroll
    for (int j = 0; j < 4; ++j)
        *(v4f*)(d + 4*j) = (v4f){out[4*j], out[4*j+1], out[4*j+2], out[4*j+3]};
}

// ---------- wave A ----------
struct A_St {
    float acr[8], aci[8];       // Acor ring
    float histr[8], histi[8];   // c' history ring
    v4f   scr[4][4];            // SC prefetch ring: scr[m&3][0..3]
    float pp_r, pp_i;           // ppre: k>=2 corrections for the UPCOMING step
    float z_re, z_im;           // vector z, d=1..5 at lanes (sl&15)==11..15
    float r_re, r_im;           // vector r, d=1..5
    float r0_r, r0_i;           // scalar r0 (d=0), uniform across lanes
    float bp;
};
struct A_Ctx {
    const float* scp; float* outp;
    float (*aring)[2][32][2]; float (*cring)[2][32][2];
    int h, sl; bool d1f, csel; int last;
};

template <int S, bool EARLY, bool TAIL>
__device__ __forceinline__ void a_pos(A_St& st, const A_Ctx& c, int SB)
{
    constexpr int s8 = S & 7, s4 = S & 3;
    constexpr int SN = S + 1, s4n = SN & 3, NCn = 4 + (SN & 3);
    const int m = SB + S;

    // ---- ON-CHAIN: v(m) = Acor(m) + ppre(m) - c'(m-1)*S_1(m-1) ----
    const float h1r = st.histr[(S + 7) & 7];
    const float h1i = st.histi[(S + 7) & 7];
    const v4f  sv1 = st.scr[s4][0];                  // {S1r,S1i,S2r,S2i}
    float vr = st.acr[s8] + st.pp_r;
    float vi = st.aci[s8] + st.pp_i;
    vr = fmaf(-h1r, sv1.x, fmaf( h1i, sv1.y, vr));
    vi = fmaf(-h1r, sv1.y, fmaf(-h1i, sv1.x, vi));

    // emit v(m) (all 32 lanes of the half uniform -> same-addr store)
    *(v2f*)(c.outp + 4 * (size_t)m + 2 * c.h) = (v2f){vr, vi};

    // ---- branch 1 (no swap dependency): vector r update + q tree over d=1..5 ----
    const float ar = OMB_C * vr, ai = OMB_C * vi;
    st.r_re = BETA_C * st.r_re + (ar * st.z_re + ai * st.z_im);
    st.r_im = BETA_C * st.r_im + (ai * st.z_re - ar * st.z_im);
    float qr = st.r_re * st.z_re + st.r_im * st.z_im;
    float qi = st.r_im * st.z_re - st.r_re * st.z_im;
    qr = rowred_bcast(qr);
    qi = rowred_bcast(qi);

    // ---- branch 2 (parallel with the tree): cross-half v + scalar d=0 ----
    float Xr = vr, Yr = vr, Xi = vi, Yi = vi;
    plane32_swap2(Xr, Yr, Xi, Yi);
    const float vlr = c.csel ? Xr : Yr;
    const float vli = c.csel ? Xi : Yi;
    // r0(m) = beta*r0(m-1) + omb * v_k(m)*conj(v_l(m))
    st.r0_r = BETA_C * st.r0_r + (ar * vlr + ai * vli);
    st.r0_i = BETA_C * st.r0_i + (ai * vlr - ar * vli);
    // q0 = r0(m)*conj(v_l(m))
    const float q0r = st.r0_r * vlr + st.r0_i * vli;
    const float q0i = st.r0_i * vlr - st.r0_r * vli;

    // ---- join + c'(m) ----
    const float qtr = qr + q0r;
    const float qti = qi + q0i;
    float i2;
    if (EARLY) {
        const float inv = __builtin_amdgcn_rcpf(1.0f - st.bp);
        st.bp *= BETA_C;
        i2 = (2.0f * LR_C) * inv;
    } else {
        i2 = 2.0f * LR_C;
    }
    const float tt = vr * vr + vi * vi;
    const float e2 = fmaf(2.0f * LR_C, tt, -(2.0f * LR_C) * R2_C);
    const float cr = fmaf(e2, vr, i2 * qtr);
    const float ci = fmaf(e2, vi, i2 * qti);

    st.histr[s8] = cr; st.histi[s8] = ci;
    *(v2f*)&c.cring[s8][c.h][c.sl][0] = (v2f){cr, ci};  // per-lane slots, conflict-free

    // ---- OFF-CHAIN tail ----
    // z shift + insert v_l(m) at d=1 (for step m+1): z(m+1)[1]=v_l(m), [d]=z(m)[d-1]
    const float zsr = dpp_mov<0x111>(st.z_re);
    const float zsi = dpp_mov<0x111>(st.z_im);
    st.z_re = c.d1f ? vlr : zsr;
    st.z_im = c.d1f ? vli : zsi;

    // ppre(m+1) = -sum_{k=2..NCn} c'(m+1-k)*S_k(m+1-k)  (two indep chains)
    {
        float p0r = 0.f, p0i = 0.f, p1r = 0.f, p1i = 0.f;
#pragma unroll
        for (int k = 2; k <= NCn; ++k) {
            const float hr = st.histr[(SN - k) & 7];
            const float hi = st.histi[(SN - k) & 7];
            const v4f sv = st.scr[s4n][(k - 1) >> 1];
            const float Sr = (k & 1) ? sv.x : sv.z;
            const float Si = (k & 1) ? sv.y : sv.w;
            if (k & 1) {
                p0r = fmaf(-hr, Sr, fmaf( hi, Si, p0r));
                p0i = fmaf(-hr, Si, fmaf(-hi, Sr, p0i));
            } else {
                p1r = fmaf(-hr, Sr, fmaf( hi, Si, p1r));
                p1i = fmaf(-hr, Si, fmaf(-hi, Sr, p1i));
            }
        }
        st.pp_r = p0r + p1r;
        st.pp_i = p0i + p1i;
    }

    // SC prefetch for m+4 into the slot just consumed
    int mp = m + 4;
    if (TAIL) { if (mp > c.last) mp = c.last; }
    const float* p = c.scp + (size_t)mp * 16;
#pragma unroll
    for (int j = 0; j < 4; ++j)
        st.scr[s4][j] = *(const v4f*)(p + 4 * j);
}

template <int I, bool EARLY, bool TAIL>
__device__ __forceinline__ void a_sub(A_St& st, const A_Ctx& c, int SB)
{
#pragma unroll
    for (int t = 0; t < 4; ++t) {
        const v2f a0 = *(const v2f*)&c.aring[(4*I + t) & 7][c.h][0][0];
        st.acr[(4*I + t) & 7] = a0.x;
        st.aci[(4*I + t) & 7] = a0.y;
    }
    a_pos<4*I + 0, EARLY, TAIL>(st, c, SB);
    a_pos<4*I + 1, EARLY, TAIL>(st, c, SB);
    a_pos<4*I + 2, EARLY, TAIL>(st, c, SB);
    a_pos<4*I + 3, EARLY, TAIL>(st, c, SB);
    wg_barrier();
}
template <bool EARLY, bool TAIL>
__device__ __forceinline__ void a_super(A_St& st, const A_Ctx& c, int SB)
{
    a_sub<0, EARLY, TAIL>(st, c, SB);
    a_sub<1, EARLY, TAIL>(st, c, SB);
    a_sub<2, EARLY, TAIL>(st, c, SB);
    a_sub<3, EARLY, TAIL>(st, c, SB);
}

// ---------- wave B (identical to round 8/10) ----------
struct B_St {
    v2f wA_r, wA_i, wB_r, wB_i;
    v4f ur[16], ui[16];
    float mA, mB;
};
struct B_Ctx {
    const float* pre; const float* pim;
    float (*aring)[2][32][2]; float (*cring)[2][32][2];
    int h, sl; int last;
};

__device__ __forceinline__ v2f b_tree(const B_St& s, const v4f& uR, const v4f& uI) {
    const v2f uA_r = {uR.x,uR.y}, uB_r = {uR.z,uR.w};
    const v2f uA_i = {uI.x,uI.y}, uB_i = {uI.z,uI.w};
    v2f tr = s.wA_r*uA_r - s.wA_i*uA_i + s.wB_r*uB_r - s.wB_i*uB_i;
    v2f ti = s.wA_r*uA_i + s.wA_i*uA_r + s.wB_r*uB_i + s.wB_i*uB_r;
    return (v2f){ rowred_bcast(tr.x + tr.y), rowred_bcast(ti.x + ti.y) };
}

template <int I, bool TAIL>
__device__ __forceinline__ void b_sub(B_St& st, const B_Ctx& c, int SB)
{
    float ccr[4], cci[4];
#pragma unroll
    for (int t = 0; t < 4; ++t) {
        const v2f cc = *(const v2f*)&c.cring[(4*I + 4 + t) & 7][c.h][0][0];
        ccr[t] = cc.x; cci[t] = cc.y;
    }
#pragma unroll
    for (int t = 0; t < 4; ++t) {
        const float crA = ccr[t] * st.mA, ciA = cci[t] * st.mA;
        const float crB = ccr[t] * st.mB, ciB = cci[t] * st.mB;
        const v4f uR = st.ur[(4*I + 12 + t) & 15], uI = st.ui[(4*I + 12 + t) & 15];
        const v2f uA_r = {uR.x,uR.y}, uB_r = {uR.z,uR.w};
        const v2f uA_i = {uI.x,uI.y}, uB_i = {uI.z,uI.w};
        st.wA_r -= (v2f){crA,crA}*uA_r + (v2f){ciA,ciA}*uA_i;
        st.wA_i -= (v2f){ciA,ciA}*uA_r - (v2f){crA,crA}*uA_i;
        st.wB_r -= (v2f){crB,crB}*uB_r + (v2f){ciB,ciB}*uB_i;
        st.wB_i -= (v2f){ciB,ciB}*uB_r - (v2f){crB,crB}*uB_i;
    }
#pragma unroll
    for (int t = 0; t < 4; ++t) {
        const v2f T = b_tree(st, st.ur[(4*I + 4 + t) & 15], st.ui[(4*I + 4 + t) & 15]);
        *(v2f*)&c.aring[(4*I + 4 + t) & 7][c.h][c.sl][0] = T;
    }
#pragma unroll
    for (int t = 0; t < 4; ++t) {
        int f = SB + 4*I + 8 + t;
        if (TAIL) { if (f > c.last) f = c.last; }
        st.ur[(4*I + 8 + t) & 15] = *(const v4f*)(c.pre + (size_t)f * FRST);
        st.ui[(4*I + 8 + t) & 15] = *(const v4f*)(c.pim + (size_t)f * FRST);
    }
    wg_barrier();
}
template <bool TAIL>
__device__ __forceinline__ void b_super(B_St& st, const B_Ctx& c, int SB)
{
    b_sub<0, TAIL>(st, c, SB);
    b_sub<1, TAIL>(st, c, SB);
    b_sub<2, TAIL>(st, c, SB);
    b_sub<3, TAIL>(st, c, SB);
}

// ---------- 2-wave block-pipelined scan ----------
__global__ void __launch_bounds__(128, 1)
__attribute__((amdgpu_waves_per_eu(1, 1)))
mucma2e_kernel(const float* __restrict__ fr_re, const float* __restrict__ fr_im,
               const float* __restrict__ w0r_in, const float* __restrict__ w0i_in,
               const float* __restrict__ scp, float* __restrict__ outp, int nsym)
{
    __shared__ __align__(16) float cring[8][2][32][2];
    __shared__ __align__(16) float aring[8][2][32][2];

    const int  tid  = threadIdx.x;
    const int  wid  = tid >> 6;
    const int  lane = tid & 63;
    const int  sl   = lane & 31;
    const int  h    = lane >> 5;
    const int  loff = (4*sl < 34) ? 4*sl : 34;
    const int  last = nsym - 1;
    const int  SBend = nsym - 16;

    bool csel;
    { const float own = h ? 11.f : 7.f; float v = own, X = own;
      plane32_swap(X, v); csel = (X != own); }

    if (wid == 0) {
        // ================= wave A (chain) =================
        A_St st; A_Ctx c;
        c.scp = scp; c.outp = outp; c.aring = aring; c.cring = cring;
        c.h = h; c.sl = sl; c.d1f = ((sl & 15) == 11); c.csel = csel; c.last = last;
#pragma unroll
        for (int k = 0; k < 8; ++k) {
            st.histr[k] = 0.f; st.histi[k] = 0.f;
            st.acr[k] = 0.f;  st.aci[k] = 0.f;
        }
        st.pp_r = 0.f; st.pp_i = 0.f;
        st.z_re = 0.f; st.z_im = 0.f;
        st.r_re = 0.f; st.r_im = 0.f;
        st.r0_r = 0.f; st.r0_i = 0.f;
        st.bp = BETA_C;
#pragma unroll
        for (int s = 0; s < 4; ++s)
#pragma unroll
            for (int j = 0; j < 4; ++j)
                st.scr[s][j] = *(const v4f*)(scp + (size_t)s * 16 + 4 * j);
        if (lane < 32) cring[lane >> 2][(lane >> 1) & 1][0][lane & 1] = 0.f;
        wg_barrier();

        int SB = 0;
        for (; SB < SPLIT_N; SB += 16) a_super<true , false>(st, c, SB);
        for (; SB < SBend;   SB += 16) a_super<false, false>(st, c, SB);
        a_super<false, true>(st, c, SB);
    } else {
        // ================= wave B (tree) =================
        B_St st; B_Ctx c;
        c.pre = fr_re + loff; c.pim = fr_im + loff;
        c.aring = aring; c.cring = cring; c.h = h; c.sl = sl; c.last = last;
        st.mA = (sl <= 8) ? 1.f : 0.f;
        st.mB = (sl <= 9) ? 1.f : 0.f;
        st.wA_r = (v2f){0.f,0.f}; st.wA_i = (v2f){0.f,0.f};
        st.wB_r = (v2f){0.f,0.f}; st.wB_i = (v2f){0.f,0.f};
        if (sl <= 8) {
            const int b = h*FRST + 2*sl;
            st.wA_r.x = w0r_in[b];       st.wA_r.y = w0r_in[b+NTAPS];
            st.wA_i.x = w0i_in[b];       st.wA_i.y = w0i_in[b+NTAPS];
            st.wB_r.x = w0r_in[b+1];     st.wB_r.y = w0r_in[b+NTAPS+1];
            st.wB_i.x = w0i_in[b+1];     st.wB_i.y = w0i_in[b+NTAPS+1];
        } else if (sl == 9) {
            st.wB_r.x = w0r_in[h*FRST+18];  st.wB_r.y = w0r_in[h*FRST+37];
            st.wB_i.x = w0i_in[h*FRST+18];  st.wB_i.y = w0i_in[h*FRST+37];
        }
#pragma unroll
        for (int k = 0; k < 12; ++k) {
            st.ur[k] = *(const v4f*)(c.pre + (size_t)k * FRST);
            st.ui[k] = *(const v4f*)(c.pim + (size_t)k * FRST);
        }
#pragma unroll
        for (int k = 12; k < 16; ++k) {
            st.ur[k] = (v4f){0.f,0.f,0.f,0.f};
            st.ui[k] = (v4f){0.f,0.f,0.f,0.f};
        }
#pragma unroll
        for (int t = 0; t < 4; ++t) {
            const v2f T = b_tree(st, st.ur[t], st.ui[t]);
            *(v2f*)&aring[t][h][sl][0] = T;
        }
        wg_barrier();

        int SB = 0;
        for (; SB < SBend; SB += 16) b_super<false>(st, c, SB);
        b_super<true>(st, c, SB);
    }
}

// ---------- fallback: round-4 single-wave kernel ----------
__global__ void __launch_bounds__(64, 1)
mucma_scan_fb(const float* __restrict__ fr_re, const float* __restrict__ fr_im,
              const float* __restrict__ w0r_in, const float* __restrict__ w0i_in,
              float* __restrict__ out, int nsym)
{
    const int  lane = threadIdx.x;
    const int  sl   = lane & 31;
    const int  h    = lane >> 5;
    const int  loff = (4 * sl < 34) ? 4 * sl : 34;
    const float mA  = (sl <= 8) ? 1.f : 0.f;
    const float mB  = (sl <= 9) ? 1.f : 0.f;
    const bool d0f  = (sl == 10);
    const bool stfl = (sl == 0);

    v2f wA_r = {0.f,0.f}, wA_i = {0.f,0.f}, wB_r = {0.f,0.f}, wB_i = {0.f,0.f};
    if (sl <= 8) {
        const int b = h * FRST + 2 * sl;
        wA_r.x = w0r_in[b];         wA_r.y = w0r_in[b + NTAPS];
        wA_i.x = w0i_in[b];         wA_i.y = w0i_in[b + NTAPS];
        wB_r.x = w0r_in[b + 1];     wB_r.y = w0r_in[b + NTAPS + 1];
        wB_i.x = w0i_in[b + 1];     wB_i.y = w0i_in[b + NTAPS + 1];
    } else if (sl == 9) {
        wB_r.x = w0r_in[h * FRST + 18];  wB_r.y = w0r_in[h * FRST + 37];
        wB_i.x = w0i_in[h * FRST + 18];  wB_i.y = w0i_in[h * FRST + 37];
    }
    float r_re = 0.f, r_im = 0.f, z_re = 0.f, z_im = 0.f;
    float bp = BETA_C;

    bool csel;
    {
        const float own = h ? 11.f : 7.f;
        float v = own, X = own;
        plane32_swap(X, v);
        csel = (X != own);
    }

    const float* pre = fr_re + loff;
    const float* pim = fr_im + loff;

    v4f rr[8], ri[8];
#pragma unroll
    for (int p = 0; p < 8; ++p) {
        const int idx = (p < nsym) ? p : (nsym - 1);
        rr[p] = *(const v4f*)(pre + (size_t)idx * FRST);
        ri[p] = *(const v4f*)(pim + (size_t)idx * FRST);
    }

    auto body = [&](int n, int p, int npf) {
        const v4f uR = rr[p], uI = ri[p];
        rr[p] = *(const v4f*)(pre + (size_t)npf * FRST);
        ri[p] = *(const v4f*)(pim + (size_t)npf * FRST);

        const v2f uA_r = {uR.x, uR.y}, uB_r = {uR.z, uR.w};
        const v2f uA_i = {uI.x, uI.y}, uB_i = {uI.z, uI.w};

        v2f tr = wA_r * uA_r - wA_i * uA_i + wB_r * uB_r - wB_i * uB_i;
        v2f ti = wA_r * uA_i + wA_i * uA_r + wB_r * uB_i + wB_i * uB_r;
        float xr = rowred_bcast(tr.x + tr.y);
        float xi = rowred_bcast(ti.x + ti.y);
        const float vkr = xr, vki = xi;

        float Xr = xr, Xi = xi;
        plane32_swap(Xr, xr);
        plane32_swap(Xi, xi);
        const float vlr = csel ? Xr : xr;
        const float vli = csel ? Xi : xi;

        const float zsr = dpp_mov<0x111>(z_re);
        const float zsi = dpp_mov<0x111>(z_im);
        z_re = d0f ? vlr : zsr;
        z_im = d0f ? vli : zsi;

        const float ar = OMB_C * vkr, ai = OMB_C * vki;
        r_re = BETA_C * r_re + (ar * z_re + ai * z_im);
        r_im = BETA_C * r_im + (ai * z_re - ar * z_im);

        float qr = r_re * z_re + r_im * z_im;
        float qi = r_im * z_re - r_re * z_im;
        qr = rowred_bcast(qr);
        qi = rowred_bcast(qi);

        const float inv = __builtin_amdgcn_rcpf(1.0f - bp);
        bp *= BETA_C;
        const float i2 = (2.0f * LR_C) * inv;
        const float ek = R2_C - (vkr * vkr + vki * vki);
        const float e2 = (-2.0f * LR_C) * ek;
        const float cr = e2 * vkr + i2 * qr;
        const float ci = e2 * vki + i2 * qi;

        const float crA = cr * mA, ciA = ci * mA;
        const float crB = cr * mB, ciB = ci * mB;
        wA_r -= (v2f){crA,crA} * uA_r + (v2f){ciA,ciA} * uA_i;
        wA_i -= (v2f){ciA,ciA} * uA_r - (v2f){crA,crA} * uA_i;
        wB_r -= (v2f){crB,crB} * uB_r + (v2f){ciB,ciB} * uB_i;
        wB_i -= (v2f){ciB,ciB} * uB_r - (v2f){crB,crB} * uB_i;

        if (stfl) {
            v2f o; o.x = vkr; o.y = vki;
            *(v2f*)(out + 4 * (size_t)n + 2 * h) = o;
        }
    };

    int NBmain = nsym / 8 - 1;
    if (NBmain < 0) NBmain = 0;
    for (int b = 0; b < NBmain; ++b) {
        const int nb = b * 8;
#pragma unroll
        for (int p = 0; p < 8; ++p) body(nb + p, p, nb + p + 8);
    }
    for (int nb = NBmain * 8; nb < nsym; nb += 8) {
#pragma unroll
        for (int p = 0; p < 8; ++p) {
            const int n = nb + p;
            if (n < nsym) {
                int npf = n + 8;
                if (npf > nsym - 1) npf = nsym - 1;
                body(n, p, npf);
            }
        }
    }
}

extern "C" void kernel_launch(void* const* d_in, const int* in_sizes, int n_in,
                              void* d_out, int out_size, void* d_ws, size_t ws_size,
                              hipStream_t stream)
{
    const float* fr_re = (const float*)d_in[0];
    const float* fr_im = (const float*)d_in[1];
    const float* w0r   = (const float*)d_in[2];
    const float* w0i   = (const float*)d_in[3];
    float* outp = (float*)d_out;
    const int nsym = in_sizes[0] / FRST;

    const bool use2 = (nsym % 16 == 0) && (nsym >= SPLIT_N + 16)
                   && (ws_size >= (size_t)nsym * 64);
    if (use2) {
        hipLaunchKernelGGL(gram7_kernel, dim3((nsym + 63) / 64), dim3(64), 0, stream,
                           fr_re, fr_im, (float*)d_ws, nsym);
        hipLaunchKernelGGL(mucma2e_kernel, dim3(1), dim3(128), 0, stream,
                           fr_re, fr_im, w0r, w0i, (const float*)d_ws, outp, nsym);
    } else {
        hipLaunchKernelGGL(mucma_scan_fb, dim3(1), dim3(64), 0, stream,
                           fr_re, fr_im, w0r, w0i, outp, nsym);
    }
}

// Round 13
// 26542.010 us; speedup vs baseline: 1.1133x; 1.0823x over previous
//
#include <hip/hip_runtime.h>
#include <stdint.h>

// MUCMA — round 13: round-8/10 kernel with ONE change: the correction sum in
// wave A is reassociated. k=2..NC terms (which depend only on c'(m-2) and
// older — available since the previous step) accumulate into two independent
// chains p0/p1 computed BEFORE the on-chain k=1 term. Zero added instructions;
// cuts the recurrence-path correction depth from ~11 dependent fmafs (~44 cyc)
// to ~3 (~12 cyc) and gives the scheduler slack to fill the previous step's
// DPP/permlane stalls and the sub-block-head acor LDS-read latency.
// Everything else (structure, wave B, gram7, rings, barriers) verbatim round 8.

typedef float v2f __attribute__((ext_vector_type(2)));
typedef float v4f __attribute__((ext_vector_type(4), aligned(8)));

constexpr int   NTAPS   = 19;
constexpr int   FRST    = 38;
constexpr float BETA_C  = 0.999f;
constexpr float OMB_C   = 0.001f;
constexpr float LR_C    = 0.0001220703125f;   // 2^-13
constexpr float R2_C    = 1.32f;
constexpr int   SPLIT_N = 24576;              // beta^(n+1) == 0 in f32 beyond; mult of 16

template <int CTRL>
__device__ __forceinline__ float dpp_add(float x) {
    return x + __int_as_float(__builtin_amdgcn_update_dpp(
        0, __float_as_int(x), CTRL, 0xF, 0xF, true));
}
template <int CTRL>
__device__ __forceinline__ float dpp_mov(float x) {
    return __int_as_float(__builtin_amdgcn_update_dpp(
        0, __float_as_int(x), CTRL, 0xF, 0xF, true));
}
__device__ __forceinline__ float rowred_bcast(float x) {
    x = dpp_add<0x121>(x);   // row_ror:1
    x = dpp_add<0x122>(x);   // row_ror:2
    x = dpp_add<0x124>(x);   // row_ror:4
    x = dpp_add<0x128>(x);   // row_ror:8
    return x;
}
__device__ __forceinline__ void plane32_swap(float& a, float& b) {
    asm("s_nop 1\n\t"
        "v_permlane32_swap_b32 %0, %1\n\t"
        "s_nop 1"
        : "+v"(a), "+v"(b));
}
__device__ __forceinline__ void plane32_swap2(float& a, float& b, float& c, float& d) {
    asm("s_nop 1\n\t"
        "v_permlane32_swap_b32 %0, %1\n\t"
        "v_permlane32_swap_b32 %2, %3\n\t"
        "s_nop 1"
        : "+v"(a), "+v"(b), "+v"(c), "+v"(d));
}
__device__ __forceinline__ void wg_barrier() {
    asm volatile("s_waitcnt lgkmcnt(0)\n\ts_barrier" ::: "memory");
}

// ---------- parallel precompute: SC[m][2(k-1)..] = S_k(m-k) = <conj u(m-k), u(m)> ----------
__global__ void __launch_bounds__(64)
gram7_kernel(const float* __restrict__ fr_re, const float* __restrict__ fr_im,
             float* __restrict__ sc, int nsym)
{
    __shared__ float lre[71 * FRST], lim[71 * FRST];
    const int lane = threadIdx.x;
    const int n0   = blockIdx.x * 64;
    const int base = (n0 - 7) * FRST;
    const long gmax = (long)nsym * FRST;
    for (int idx = lane; idx < 71 * FRST; idx += 64) {
        const long g = (long)base + idx;
        float a = 0.f, b = 0.f;
        if (g >= 0 && g < gmax) { a = fr_re[g]; b = fr_im[g]; }
        lre[idx] = a; lim[idx] = b;
    }
    __syncthreads();
    const int m = n0 + lane;
    if (m >= nsym) return;
    const float* br = lre + (lane + 7) * FRST;
    const float* bi = lim + (lane + 7) * FRST;
    float out[16];
#pragma unroll
    for (int k = 1; k <= 7; ++k) {
        const float* ar = br - k * FRST;
        const float* ai = bi - k * FRST;
        float sr = 0.f, si = 0.f;
#pragma unroll
        for (int e = 0; e < FRST; ++e) {
            sr = fmaf(ar[e], br[e], fmaf(ai[e], bi[e], sr));
            si = fmaf(-ai[e], br[e], fmaf(ar[e], bi[e], si));
        }
        const bool ok = (m >= k);
        out[2*(k-1)]   = ok ? sr : 0.f;
        out[2*(k-1)+1] = ok ? si : 0.f;
    }
    out[14] = 0.f; out[15] = 0.f;
    float* d = sc + (size_t)m * 16;
#pragma unroll
    for (int j = 0; j < 4; ++j)
        *(v4f*)(d + 4*j) = (v4f){out[4*j], out[4*j+1], out[4*j+2], out[4*j+3]};
}

// ---------- wave A ----------
struct A_St {
    float acr[8], aci[8];       // Acor ring (static idx)
    float histr[8], histi[8];   // c' history ring
    v4f   scr[4][4];            // SC prefetch ring: scr[m&3][0..3]
    float z_re, z_im, r_re, r_im, bp;
};
struct A_Ctx {
    const float* scp; float* outp;
    float (*aring)[2][32][2]; float (*cring)[2][32][2];
    int h, sl; bool d0f, csel; int last;
};

template <int S, bool EARLY, bool TAIL>
__device__ __forceinline__ void a_pos(A_St& st, const A_Ctx& c, int SB)
{
    constexpr int s8 = S & 7, s4 = S & 3, NC = 4 + (S & 3);
    const int m = SB + S;

    // ---- k>=2 correction terms: two independent off-chain fma chains.
    // They read c'(m-2) and older -> values exist since the previous step, so
    // the scheduler can overlap this block with step m-1's cross-lane stalls.
    float p0r = 0.f, p0i = 0.f, p1r = 0.f, p1i = 0.f;
#pragma unroll
    for (int k = 2; k <= NC; ++k) {
        const float hr = st.histr[(S - k) & 7];
        const float hi = st.histi[(S - k) & 7];
        const v4f sv = st.scr[s4][(k - 1) >> 1];
        const float Sr = (k & 1) ? sv.x : sv.z;
        const float Si = (k & 1) ? sv.y : sv.w;
        if (k & 1) {
            p0r = fmaf(-hr, Sr, fmaf( hi, Si, p0r));
            p0i = fmaf(-hr, Si, fmaf(-hi, Sr, p0i));
        } else {
            p1r = fmaf(-hr, Sr, fmaf( hi, Si, p1r));
            p1i = fmaf(-hr, Si, fmaf(-hi, Sr, p1i));
        }
    }

    // ---- ON-CHAIN: v(m) = (Acor + p0 + p1) - c'(m-1)*S_1(m-1) ----
    const float h1r = st.histr[(S + 7) & 7];
    const float h1i = st.histi[(S + 7) & 7];
    const v4f  sv1 = st.scr[s4][0];                  // {S1r,S1i,S2r,S2i}
    float vr = st.acr[s8] + (p0r + p1r);
    float vi = st.aci[s8] + (p0i + p1i);
    vr = fmaf(-h1r, sv1.x, fmaf( h1i, sv1.y, vr));
    vi = fmaf(-h1r, sv1.y, fmaf(-h1i, sv1.x, vi));

    // emit v(m): all 32 lanes of the half carry identical data -> same-addr store
    *(v2f*)(c.outp + 4 * (size_t)m + 2 * c.h) = (v2f){vr, vi};

    // cross-half v
    float Xr = vr, Yr = vr, Xi = vi, Yi = vi;
    plane32_swap2(Xr, Yr, Xi, Yi);
    const float vlr = c.csel ? Xr : Yr;
    const float vli = c.csel ? Xi : Yi;

    // z shift / insert
    const float zsr = dpp_mov<0x111>(st.z_re);
    const float zsi = dpp_mov<0x111>(st.z_im);
    st.z_re = c.d0f ? vlr : zsr;
    st.z_im = c.d0f ? vli : zsi;

    // r = beta*r + (1-beta)*v_k*conj(z)
    const float ar = OMB_C * vr, ai = OMB_C * vi;
    st.r_re = BETA_C * st.r_re + (ar * st.z_re + ai * st.z_im);
    st.r_im = BETA_C * st.r_im + (ai * st.z_re - ar * st.z_im);

    // mu partials + row-broadcast sum
    float qr = st.r_re * st.z_re + st.r_im * st.z_im;
    float qi = st.r_im * st.z_re - st.r_re * st.z_im;
    qr = rowred_bcast(qr);
    qi = rowred_bcast(qi);

    float i2;
    if (EARLY) {
        const float inv = __builtin_amdgcn_rcpf(1.0f - st.bp);
        st.bp *= BETA_C;
        i2 = (2.0f * LR_C) * inv;
    } else {
        i2 = 2.0f * LR_C;
    }
    const float t  = vr * vr + vi * vi;
    const float e2 = fmaf(2.0f * LR_C, t, -(2.0f * LR_C) * R2_C);
    const float cr = fmaf(e2, vr, i2 * qr);
    const float ci = fmaf(e2, vi, i2 * qi);

    st.histr[s8] = cr; st.histi[s8] = ci;
    *(v2f*)&c.cring[s8][c.h][c.sl][0] = (v2f){cr, ci};  // per-lane slots, conflict-free

    // SC prefetch for m+4 into the slot just consumed
    int mp = m + 4;
    if (TAIL) { if (mp > c.last) mp = c.last; }
    const float* p = c.scp + (size_t)mp * 16;
#pragma unroll
    for (int j = 0; j < 4; ++j)
        st.scr[s4][j] = *(const v4f*)(p + 4 * j);
}

template <int I, bool EARLY, bool TAIL>
__device__ __forceinline__ void a_sub(A_St& st, const A_Ctx& c, int SB)
{
    // Acor reads for this block (published by B one barrier ago; broadcast reads)
#pragma unroll
    for (int t = 0; t < 4; ++t) {
        const v2f a0 = *(const v2f*)&c.aring[(4*I + t) & 7][c.h][0][0];
        st.acr[(4*I + t) & 7] = a0.x;
        st.aci[(4*I + t) & 7] = a0.y;
    }
    a_pos<4*I + 0, EARLY, TAIL>(st, c, SB);
    a_pos<4*I + 1, EARLY, TAIL>(st, c, SB);
    a_pos<4*I + 2, EARLY, TAIL>(st, c, SB);
    a_pos<4*I + 3, EARLY, TAIL>(st, c, SB);
    wg_barrier();
}
template <bool EARLY, bool TAIL>
__device__ __forceinline__ void a_super(A_St& st, const A_Ctx& c, int SB)
{
    a_sub<0, EARLY, TAIL>(st, c, SB);
    a_sub<1, EARLY, TAIL>(st, c, SB);
    a_sub<2, EARLY, TAIL>(st, c, SB);
    a_sub<3, EARLY, TAIL>(st, c, SB);
}

// ---------- wave B (identical to round 8/10) ----------
struct B_St {
    v2f wA_r, wA_i, wB_r, wB_i;
    v4f ur[16], ui[16];
    float mA, mB;
};
struct B_Ctx {
    const float* pre; const float* pim;
    float (*aring)[2][32][2]; float (*cring)[2][32][2];
    int h, sl; int last;
};

__device__ __forceinline__ v2f b_tree(const B_St& s, const v4f& uR, const v4f& uI) {
    const v2f uA_r = {uR.x,uR.y}, uB_r = {uR.z,uR.w};
    const v2f uA_i = {uI.x,uI.y}, uB_i = {uI.z,uI.w};
    v2f tr = s.wA_r*uA_r - s.wA_i*uA_i + s.wB_r*uB_r - s.wB_i*uB_i;
    v2f ti = s.wA_r*uA_i + s.wA_i*uA_r + s.wB_r*uB_i + s.wB_i*uB_r;
    return (v2f){ rowred_bcast(tr.x + tr.y), rowred_bcast(ti.x + ti.y) };
}

template <int I, bool TAIL>
__device__ __forceinline__ void b_sub(B_St& st, const B_Ctx& c, int SB)
{
    float ccr[4], cci[4];
#pragma unroll
    for (int t = 0; t < 4; ++t) {
        const v2f cc = *(const v2f*)&c.cring[(4*I + 4 + t) & 7][c.h][0][0];
        ccr[t] = cc.x; cci[t] = cc.y;
    }
#pragma unroll
    for (int t = 0; t < 4; ++t) {
        const float crA = ccr[t] * st.mA, ciA = cci[t] * st.mA;
        const float crB = ccr[t] * st.mB, ciB = cci[t] * st.mB;
        const v4f uR = st.ur[(4*I + 12 + t) & 15], uI = st.ui[(4*I + 12 + t) & 15];
        const v2f uA_r = {uR.x,uR.y}, uB_r = {uR.z,uR.w};
        const v2f uA_i = {uI.x,uI.y}, uB_i = {uI.z,uI.w};
        st.wA_r -= (v2f){crA,crA}*uA_r + (v2f){ciA,ciA}*uA_i;
        st.wA_i -= (v2f){ciA,ciA}*uA_r - (v2f){crA,crA}*uA_i;
        st.wB_r -= (v2f){crB,crB}*uB_r + (v2f){ciB,ciB}*uB_i;
        st.wB_i -= (v2f){ciB,ciB}*uB_r - (v2f){crB,crB}*uB_i;
    }
#pragma unroll
    for (int t = 0; t < 4; ++t) {
        const v2f T = b_tree(st, st.ur[(4*I + 4 + t) & 15], st.ui[(4*I + 4 + t) & 15]);
        *(v2f*)&c.aring[(4*I + 4 + t) & 7][c.h][c.sl][0] = T;
    }
#pragma unroll
    for (int t = 0; t < 4; ++t) {
        int f = SB + 4*I + 8 + t;
        if (TAIL) { if (f > c.last) f = c.last; }
        st.ur[(4*I + 8 + t) & 15] = *(const v4f*)(c.pre + (size_t)f * FRST);
        st.ui[(4*I + 8 + t) & 15] = *(const v4f*)(c.pim + (size_t)f * FRST);
    }
    wg_barrier();
}
template <bool TAIL>
__device__ __forceinline__ void b_super(B_St& st, const B_Ctx& c, int SB)
{
    b_sub<0, TAIL>(st, c, SB);
    b_sub<1, TAIL>(st, c, SB);
    b_sub<2, TAIL>(st, c, SB);
    b_sub<3, TAIL>(st, c, SB);
}

// ---------- 2-wave block-pipelined scan ----------
__global__ void __launch_bounds__(128, 1)
__attribute__((amdgpu_waves_per_eu(1, 1)))
mucma2f_kernel(const float* __restrict__ fr_re, const float* __restrict__ fr_im,
               const float* __restrict__ w0r_in, const float* __restrict__ w0i_in,
               const float* __restrict__ scp, float* __restrict__ outp, int nsym)
{
    __shared__ __align__(16) float cring[8][2][32][2];
    __shared__ __align__(16) float aring[8][2][32][2];

    const int  tid  = threadIdx.x;
    const int  wid  = tid >> 6;
    const int  lane = tid & 63;
    const int  sl   = lane & 31;
    const int  h    = lane >> 5;
    const int  loff = (4*sl < 34) ? 4*sl : 34;
    const int  last = nsym - 1;
    const int  SBend = nsym - 16;

    bool csel;
    { const float own = h ? 11.f : 7.f; float v = own, X = own;
      plane32_swap(X, v); csel = (X != own); }

    if (wid == 0) {
        // ================= wave A (chain) =================
        A_St st; A_Ctx c;
        c.scp = scp; c.outp = outp; c.aring = aring; c.cring = cring;
        c.h = h; c.sl = sl; c.d0f = ((sl & 15) == 10); c.csel = csel; c.last = last;
#pragma unroll
        for (int k = 0; k < 8; ++k) {
            st.histr[k] = 0.f; st.histi[k] = 0.f;
            st.acr[k] = 0.f;  st.aci[k] = 0.f;
        }
        st.z_re = 0.f; st.z_im = 0.f; st.r_re = 0.f; st.r_im = 0.f; st.bp = BETA_C;
#pragma unroll
        for (int s = 0; s < 4; ++s)
#pragma unroll
            for (int j = 0; j < 4; ++j)
                st.scr[s][j] = *(const v4f*)(scp + (size_t)s * 16 + 4 * j);
        // zero cring broadcast entries (c' of block -1 = 0)
        if (lane < 32) cring[lane >> 2][(lane >> 1) & 1][0][lane & 1] = 0.f;
        wg_barrier();

        int SB = 0;
        for (; SB < SPLIT_N; SB += 16) a_super<true , false>(st, c, SB);
        for (; SB < SBend;   SB += 16) a_super<false, false>(st, c, SB);
        a_super<false, true>(st, c, SB);
    } else {
        // ================= wave B (tree) =================
        B_St st; B_Ctx c;
        c.pre = fr_re + loff; c.pim = fr_im + loff;
        c.aring = aring; c.cring = cring; c.h = h; c.sl = sl; c.last = last;
        st.mA = (sl <= 8) ? 1.f : 0.f;
        st.mB = (sl <= 9) ? 1.f : 0.f;
        st.wA_r = (v2f){0.f,0.f}; st.wA_i = (v2f){0.f,0.f};
        st.wB_r = (v2f){0.f,0.f}; st.wB_i = (v2f){0.f,0.f};
        if (sl <= 8) {
            const int b = h*FRST + 2*sl;
            st.wA_r.x = w0r_in[b];       st.wA_r.y = w0r_in[b+NTAPS];
            st.wA_i.x = w0i_in[b];       st.wA_i.y = w0i_in[b+NTAPS];
            st.wB_r.x = w0r_in[b+1];     st.wB_r.y = w0r_in[b+NTAPS+1];
            st.wB_i.x = w0i_in[b+1];     st.wB_i.y = w0i_in[b+NTAPS+1];
        } else if (sl == 9) {
            st.wB_r.x = w0r_in[h*FRST+18];  st.wB_r.y = w0r_in[h*FRST+37];
            st.wB_i.x = w0i_in[h*FRST+18];  st.wB_i.y = w0i_in[h*FRST+37];
        }
#pragma unroll
        for (int k = 0; k < 12; ++k) {
            st.ur[k] = *(const v4f*)(c.pre + (size_t)k * FRST);
            st.ui[k] = *(const v4f*)(c.pim + (size_t)k * FRST);
        }
#pragma unroll
        for (int k = 12; k < 16; ++k) {
            st.ur[k] = (v4f){0.f,0.f,0.f,0.f};
            st.ui[k] = (v4f){0.f,0.f,0.f,0.f};
        }
        // prologue: Acor for block 0 (W = w0)
#pragma unroll
        for (int t = 0; t < 4; ++t) {
            const v2f T = b_tree(st, st.ur[t], st.ui[t]);
            *(v2f*)&aring[t][h][sl][0] = T;
        }
        wg_barrier();

        int SB = 0;
        for (; SB < SBend; SB += 16) b_super<false>(st, c, SB);
        b_super<true>(st, c, SB);
    }
}

// ---------- fallback: round-4 single-wave kernel ----------
__global__ void __launch_bounds__(64, 1)
mucma_scan_fb(const float* __restrict__ fr_re, const float* __restrict__ fr_im,
              const float* __restrict__ w0r_in, const float* __restrict__ w0i_in,
              float* __restrict__ out, int nsym)
{
    const int  lane = threadIdx.x;
    const int  sl   = lane & 31;
    const int  h    = lane >> 5;
    const int  loff = (4 * sl < 34) ? 4 * sl : 34;
    const float mA  = (sl <= 8) ? 1.f : 0.f;
    const float mB  = (sl <= 9) ? 1.f : 0.f;
    const bool d0f  = (sl == 10);
    const bool stfl = (sl == 0);

    v2f wA_r = {0.f,0.f}, wA_i = {0.f,0.f}, wB_r = {0.f,0.f}, wB_i = {0.f,0.f};
    if (sl <= 8) {
        const int b = h * FRST + 2 * sl;
        wA_r.x = w0r_in[b];         wA_r.y = w0r_in[b + NTAPS];
        wA_i.x = w0i_in[b];         wA_i.y = w0i_in[b + NTAPS];
        wB_r.x = w0r_in[b + 1];     wB_r.y = w0r_in[b + NTAPS + 1];
        wB_i.x = w0i_in[b + 1];     wB_i.y = w0i_in[b + NTAPS + 1];
    } else if (sl == 9) {
        wB_r.x = w0r_in[h * FRST + 18];  wB_r.y = w0r_in[h * FRST + 37];
        wB_i.x = w0i_in[h * FRST + 18];  wB_i.y = w0i_in[h * FRST + 37];
    }
    float r_re = 0.f, r_im = 0.f, z_re = 0.f, z_im = 0.f;
    float bp = BETA_C;

    bool csel;
    {
        const float own = h ? 11.f : 7.f;
        float v = own, X = own;
        plane32_swap(X, v);
        csel = (X != own);
    }

    const float* pre = fr_re + loff;
    const float* pim = fr_im + loff;

    v4f rr[8], ri[8];
#pragma unroll
    for (int p = 0; p < 8; ++p) {
        const int idx = (p < nsym) ? p : (nsym - 1);
        rr[p] = *(const v4f*)(pre + (size_t)idx * FRST);
        ri[p] = *(const v4f*)(pim + (size_t)idx * FRST);
    }

    auto body = [&](int n, int p, int npf) {
        const v4f uR = rr[p], uI = ri[p];
        rr[p] = *(const v4f*)(pre + (size_t)npf * FRST);
        ri[p] = *(const v4f*)(pim + (size_t)npf * FRST);

        const v2f uA_r = {uR.x, uR.y}, uB_r = {uR.z, uR.w};
        const v2f uA_i = {uI.x, uI.y}, uB_i = {uI.z, uI.w};

        v2f tr = wA_r * uA_r - wA_i * uA_i + wB_r * uB_r - wB_i * uB_i;
        v2f ti = wA_r * uA_i + wA_i * uA_r + wB_r * uB_i + wB_i * uB_r;
        float xr = rowred_bcast(tr.x + tr.y);
        float xi = rowred_bcast(ti.x + ti.y);
        const float vkr = xr, vki = xi;

        float Xr = xr, Xi = xi;
        plane32_swap(Xr, xr);
        plane32_swap(Xi, xi);
        const float vlr = csel ? Xr : xr;
        const float vli = csel ? Xi : xi;

        const float zsr = dpp_mov<0x111>(z_re);
        const float zsi = dpp_mov<0x111>(z_im);
        z_re = d0f ? vlr : zsr;
        z_im = d0f ? vli : zsi;

        const float ar = OMB_C * vkr, ai = OMB_C * vki;
        r_re = BETA_C * r_re + (ar * z_re + ai * z_im);
        r_im = BETA_C * r_im + (ai * z_re - ar * z_im);

        float qr = r_re * z_re + r_im * z_im;
        float qi = r_im * z_re - r_re * z_im;
        qr = rowred_bcast(qr);
        qi = rowred_bcast(qi);

        const float inv = __builtin_amdgcn_rcpf(1.0f - bp);
        bp *= BETA_C;
        const float i2 = (2.0f * LR_C) * inv;
        const float ek = R2_C - (vkr * vkr + vki * vki);
        const float e2 = (-2.0f * LR_C) * ek;
        const float cr = e2 * vkr + i2 * qr;
        const float ci = e2 * vki + i2 * qi;

        const float crA = cr * mA, ciA = ci * mA;
        const float crB = cr * mB, ciB = ci * mB;
        wA_r -= (v2f){crA,crA} * uA_r + (v2f){ciA,ciA} * uA_i;
        wA_i -= (v2f){ciA,ciA} * uA_r - (v2f){crA,crA} * uA_i;
        wB_r -= (v2f){crB,crB} * uB_r + (v2f){ciB,ciB} * uB_i;
        wB_i -= (v2f){ciB,ciB} * uB_r - (v2f){crB,crB} * uB_i;

        if (stfl) {
            v2f o; o.x = vkr; o.y = vki;
            *(v2f*)(out + 4 * (size_t)n + 2 * h) = o;
        }
    };

    int NBmain = nsym / 8 - 1;
    if (NBmain < 0) NBmain = 0;
    for (int b = 0; b < NBmain; ++b) {
        const int nb = b * 8;
#pragma unroll
        for (int p = 0; p < 8; ++p) body(nb + p, p, nb + p + 8);
    }
    for (int nb = NBmain * 8; nb < nsym; nb += 8) {
#pragma unroll
        for (int p = 0; p < 8; ++p) {
            const int n = nb + p;
            if (n < nsym) {
                int npf = n + 8;
                if (npf > nsym - 1) npf = nsym - 1;
                body(n, p, npf);
            }
        }
    }
}

extern "C" void kernel_launch(void* const* d_in, const int* in_sizes, int n_in,
                              void* d_out, int out_size, void* d_ws, size_t ws_size,
                              hipStream_t stream)
{
    const float* fr_re = (const float*)d_in[0];
    const float* fr_im = (const float*)d_in[1];
    const float* w0r   = (const float*)d_in[2];
    const float* w0i   = (const float*)d_in[3];
    float* outp = (float*)d_out;
    const int nsym = in_sizes[0] / FRST;

    const bool use2 = (nsym % 16 == 0) && (nsym >= SPLIT_N + 16)
                   && (ws_size >= (size_t)nsym * 64);
    if (use2) {
        hipLaunchKernelGGL(gram7_kernel, dim3((nsym + 63) / 64), dim3(64), 0, stream,
                           fr_re, fr_im, (float*)d_ws, nsym);
        hipLaunchKernelGGL(mucma2f_kernel, dim3(1), dim3(128), 0, stream,
                           fr_re, fr_im, w0r, w0i, (const float*)d_ws, outp, nsym);
    } else {
        hipLaunchKernelGGL(mucma_scan_fb, dim3(1), dim3(64), 0, stream,
                           fr_re, fr_im, w0r, w0i, outp, nsym);
    }
}